// Round 1
// baseline (582.847 us; speedup 1.0000x reference)
//
#include <hip/hip_runtime.h>
#include <cstdint>
#include <cstddef>

#define B_ 16384
#define F_ 4096
#define P_ 32
#define D_ 128
#define STRIPS 16      // strips per partition; grid = P_*STRIPS = 512 blocks
#define TILES 32       // row-tiles (BM=32) per strip: 16384 / (STRIPS*32)

using f32x4 = __attribute__((ext_vector_type(4))) float;
using s16x8 = __attribute__((ext_vector_type(8))) short;

__device__ inline unsigned short bf16_rn(float f) {
    union { float f; uint32_t u; } v; v.f = f;
    uint32_t u = v.u;
    return (unsigned short)((u + 0x7FFFu + ((u >> 16) & 1u)) >> 16);
}
__device__ inline float bf16_to_f32(unsigned short h) {
    union { uint32_t u; float f; } v; v.u = ((uint32_t)h) << 16;
    return v.f;
}
__device__ inline float fast_tanh(float z) {
    // 1 - 2/(e^{2z}+1): saturates correctly at +/-inf, no NaN for finite z
    float e = __expf(2.f * z);
    return 1.f - 2.f / (e + 1.f);
}

// Stage W[p] (128x128 f32, row-major [k][c]) into LDS transposed WT[c][k] as
// bf16 hi + lo residual, XOR-swizzled: byte = c*256 + ((2k) ^ ((c&7)<<4)).
__device__ inline void stage_w(const float* __restrict__ Wp,
                               short* s_whi, short* s_wlo, int tid) {
    for (int it = 0; it < 32; ++it) {
        int idx = it * 256 + tid;          // 8192 (c, k-pair) items
        int c  = idx & 127;
        int kp = idx >> 7;                 // 0..63 -> k = 2kp, 2kp+1
        float w0 = Wp[(2 * kp) * D_ + c];
        float w1 = Wp[(2 * kp + 1) * D_ + c];
        unsigned short h0 = bf16_rn(w0), h1 = bf16_rn(w1);
        float l0 = w0 - bf16_to_f32(h0);
        float l1 = w1 - bf16_to_f32(h1);
        unsigned short g0 = bf16_rn(l0), g1 = bf16_rn(l1);
        uint32_t hi = (uint32_t)h0 | ((uint32_t)h1 << 16);
        uint32_t lo = (uint32_t)g0 | ((uint32_t)g1 << 16);
        int boff = c * 256 + ((4 * kp) ^ ((c & 7) << 4));
        *(uint32_t*)((char*)s_whi + boff) = hi;
        *(uint32_t*)((char*)s_wlo + boff) = lo;
    }
}

__device__ inline s16x8 read_b(const short* s_w, int col, int skbytes) {
    int boff = col * 256 + (skbytes ^ ((col & 7) << 4));
    return *(const s16x8*)((const char*)s_w + boff);
}

// ---------------- GEMM1: y1 = x @ BD(W1) + bias1, fused col sum/sumsq ------
__global__ __launch_bounds__(256) void k_gemm1(
    const float* __restrict__ x, const float* __restrict__ W1,
    const float* __restrict__ bias1, float* __restrict__ y1,
    float* __restrict__ sum1, float* __restrict__ sumsq1)
{
    __shared__ short s_whi[D_ * D_];
    __shared__ short s_wlo[D_ * D_];
    const int tid = threadIdx.x;
    const int bid = blockIdx.x;
    const int p = bid / STRIPS;
    const int strip = bid % STRIPS;
    stage_w(W1 + (size_t)p * D_ * D_, s_whi, s_wlo, tid);
    __syncthreads();

    const int wave = tid >> 6, lane = tid & 63;
    const int l15 = lane & 15, l4 = lane >> 4;
    const int colbase = wave * 32;

    float bi[2]; int gcol[2];
#pragma unroll
    for (int j = 0; j < 2; ++j) {
        gcol[j] = p * D_ + colbase + j * 16 + l15;
        bi[j] = bias1[gcol[j]];
    }
    float csum[2] = {0.f, 0.f}, csq[2] = {0.f, 0.f};

    for (int it = 0; it < TILES; ++it) {
        const int m0 = strip * (TILES * 32) + it * 32;
        // A tile fragments straight from global (128B/row segments)
        f32x4 av[2][4][2];
#pragma unroll
        for (int i = 0; i < 2; ++i)
#pragma unroll
            for (int s = 0; s < 4; ++s) {
                const float* ptr = x + (size_t)(m0 + i * 16 + l15) * F_
                                     + p * D_ + s * 32 + l4 * 8;
                av[i][s][0] = *(const f32x4*)ptr;
                av[i][s][1] = *(const f32x4*)(ptr + 4);
            }
        f32x4 zero = {0.f, 0.f, 0.f, 0.f};
        f32x4 acc[2][2];
#pragma unroll
        for (int i = 0; i < 2; ++i)
#pragma unroll
            for (int j = 0; j < 2; ++j) acc[i][j] = zero;

#pragma unroll
        for (int s = 0; s < 4; ++s) {
            s16x8 a[2];
#pragma unroll
            for (int i = 0; i < 2; ++i)
#pragma unroll
                for (int t = 0; t < 4; ++t) {
                    a[i][t]     = (short)bf16_rn(av[i][s][0][t]);
                    a[i][t + 4] = (short)bf16_rn(av[i][s][1][t]);
                }
            const int sk = s * 64 + l4 * 16;
#pragma unroll
            for (int j = 0; j < 2; ++j) {
                const int col = colbase + j * 16 + l15;
                s16x8 bh = read_b(s_whi, col, sk);
                s16x8 bl = read_b(s_wlo, col, sk);
#pragma unroll
                for (int i = 0; i < 2; ++i) {
                    acc[i][j] = __builtin_amdgcn_mfma_f32_16x16x32_bf16(a[i], bh, acc[i][j], 0, 0, 0);
                    acc[i][j] = __builtin_amdgcn_mfma_f32_16x16x32_bf16(a[i], bl, acc[i][j], 0, 0, 0);
                }
            }
        }
        // epilogue: +bias, store, accumulate column stats in registers
#pragma unroll
        for (int i = 0; i < 2; ++i)
#pragma unroll
            for (int j = 0; j < 2; ++j)
#pragma unroll
                for (int r = 0; r < 4; ++r) {
                    float v = acc[i][j][r] + bi[j];
                    int row = m0 + i * 16 + l4 * 4 + r;
                    y1[(size_t)row * F_ + gcol[j]] = v;
                    csum[j] += v;
                    csq[j]  += v * v;
                }
    }
#pragma unroll
    for (int j = 0; j < 2; ++j) {
        float s = csum[j], q = csq[j];
        s += __shfl_xor(s, 16); q += __shfl_xor(q, 16);
        s += __shfl_xor(s, 32); q += __shfl_xor(q, 32);
        if (l4 == 0) {
            atomicAdd(&sum1[gcol[j]], s);
            atomicAdd(&sumsq1[gcol[j]], q);
        }
    }
}

// ---- GEMM2: y3 = tanh(bn1(y1)) @ BD(W2) + bias2 + x, in place over y1 -----
__global__ __launch_bounds__(256) void k_gemm2(
    const float* __restrict__ x, float* yb /* y1 in, y3 out (aliases) */,
    const float* __restrict__ W2, const float* __restrict__ bias2,
    const float* __restrict__ scale1, const float* __restrict__ shift1,
    float* __restrict__ sum3, float* __restrict__ sumsq3)
{
    __shared__ short s_whi[D_ * D_];
    __shared__ short s_wlo[D_ * D_];
    __shared__ float s_sc[D_];
    __shared__ float s_sh[D_];
    const int tid = threadIdx.x;
    const int bid = blockIdx.x;
    const int p = bid / STRIPS;
    const int strip = bid % STRIPS;
    stage_w(W2 + (size_t)p * D_ * D_, s_whi, s_wlo, tid);
    if (tid < D_) {
        s_sc[tid] = scale1[p * D_ + tid];
        s_sh[tid] = shift1[p * D_ + tid];
    }
    __syncthreads();

    const int wave = tid >> 6, lane = tid & 63;
    const int l15 = lane & 15, l4 = lane >> 4;
    const int colbase = wave * 32;

    float bi[2]; int gcol[2];
#pragma unroll
    for (int j = 0; j < 2; ++j) {
        gcol[j] = p * D_ + colbase + j * 16 + l15;
        bi[j] = bias2[gcol[j]];
    }
    float csum[2] = {0.f, 0.f}, csq[2] = {0.f, 0.f};

    for (int it = 0; it < TILES; ++it) {
        const int m0 = strip * (TILES * 32) + it * 32;
        f32x4 av[2][4][2];
#pragma unroll
        for (int i = 0; i < 2; ++i)
#pragma unroll
            for (int s = 0; s < 4; ++s) {
                const float* ptr = yb + (size_t)(m0 + i * 16 + l15) * F_
                                      + p * D_ + s * 32 + l4 * 8;
                av[i][s][0] = *(const f32x4*)ptr;
                av[i][s][1] = *(const f32x4*)(ptr + 4);
            }
        f32x4 zero = {0.f, 0.f, 0.f, 0.f};
        f32x4 acc[2][2];
#pragma unroll
        for (int i = 0; i < 2; ++i)
#pragma unroll
            for (int j = 0; j < 2; ++j) acc[i][j] = zero;

#pragma unroll
        for (int s = 0; s < 4; ++s) {
            s16x8 a[2];
#pragma unroll
            for (int i = 0; i < 2; ++i)
#pragma unroll
                for (int h = 0; h < 2; ++h)
#pragma unroll
                    for (int t = 0; t < 4; ++t) {
                        int kk = s * 32 + l4 * 8 + h * 4 + t;
                        float z = s_sc[kk] * av[i][s][h][t] + s_sh[kk];
                        a[i][h * 4 + t] = (short)bf16_rn(fast_tanh(z));
                    }
            const int sk = s * 64 + l4 * 16;
#pragma unroll
            for (int j = 0; j < 2; ++j) {
                const int col = colbase + j * 16 + l15;
                s16x8 bh = read_b(s_whi, col, sk);
                s16x8 bl = read_b(s_wlo, col, sk);
#pragma unroll
                for (int i = 0; i < 2; ++i) {
                    acc[i][j] = __builtin_amdgcn_mfma_f32_16x16x32_bf16(a[i], bh, acc[i][j], 0, 0, 0);
                    acc[i][j] = __builtin_amdgcn_mfma_f32_16x16x32_bf16(a[i], bl, acc[i][j], 0, 0, 0);
                }
            }
        }
        // all waves of the block have consumed this y1 tile (vmcnt drained by
        // the barrier) before anyone overwrites it with y3
        __syncthreads();
#pragma unroll
        for (int i = 0; i < 2; ++i)
#pragma unroll
            for (int j = 0; j < 2; ++j)
#pragma unroll
                for (int r = 0; r < 4; ++r) {
                    int row = m0 + i * 16 + l4 * 4 + r;
                    float v = acc[i][j][r] + bi[j]
                            + x[(size_t)row * F_ + gcol[j]];
                    yb[(size_t)row * F_ + gcol[j]] = v;
                    csum[j] += v;
                    csq[j]  += v * v;
                }
    }
#pragma unroll
    for (int j = 0; j < 2; ++j) {
        float s = csum[j], q = csq[j];
        s += __shfl_xor(s, 16); q += __shfl_xor(q, 16);
        s += __shfl_xor(s, 32); q += __shfl_xor(q, 32);
        if (l4 == 0) {
            atomicAdd(&sum3[gcol[j]], s);
            atomicAdd(&sumsq3[gcol[j]], q);
        }
    }
}

// ---------------- BN finalize: scale/shift per feature ---------------------
__global__ void k_finalize(const float* __restrict__ sum,
                           const float* __restrict__ sumsq,
                           const float* __restrict__ gamma,
                           const float* __restrict__ beta,
                           float* __restrict__ scale,
                           float* __restrict__ shift)
{
    int f = blockIdx.x * blockDim.x + threadIdx.x;
    if (f < F_) {
        float mean = sum[f] * (1.f / B_);
        float var  = sumsq[f] * (1.f / B_) - mean * mean;
        float rstd = rsqrtf(var + 1e-5f);
        float sc = gamma[f] * rstd;
        scale[f] = sc;
        shift[f] = beta[f] - mean * sc;
    }
}

// ---------------- final elementwise: o3 = tanh(bn3(y3)), in place ----------
__global__ void k_bn_tanh(float* yb, const float* __restrict__ scale3,
                          const float* __restrict__ shift3)
{
    const size_t n4 = (size_t)B_ * F_ / 4;
    size_t i = (size_t)blockIdx.x * blockDim.x + threadIdx.x;
    const size_t stride = (size_t)gridDim.x * blockDim.x;
    for (; i < n4; i += stride) {
        f32x4 v = ((const f32x4*)yb)[i];
        int col = (int)((i * 4) & (F_ - 1));
        f32x4 sc = *(const f32x4*)(scale3 + col);
        f32x4 sh = *(const f32x4*)(shift3 + col);
        f32x4 r;
#pragma unroll
        for (int t = 0; t < 4; ++t) r[t] = fast_tanh(sc[t] * v[t] + sh[t]);
        ((f32x4*)yb)[i] = r;
    }
}

extern "C" void kernel_launch(void* const* d_in, const int* in_sizes, int n_in,
                              void* d_out, int out_size, void* d_ws, size_t ws_size,
                              hipStream_t stream) {
    const float* x      = (const float*)d_in[0];
    const float* W1     = (const float*)d_in[1];
    const float* bias1  = (const float*)d_in[2];
    const float* W2     = (const float*)d_in[3];
    const float* bias2  = (const float*)d_in[4];
    const float* gamma1 = (const float*)d_in[5];
    const float* beta1  = (const float*)d_in[6];
    const float* gamma3 = (const float*)d_in[7];
    const float* beta3  = (const float*)d_in[8];

    float* yb = (float*)d_out;          // y1 -> y3 -> o3, all in d_out
    float* S  = (float*)d_ws;           // 8 x 4096 f32 stats
    float* sum1   = S;
    float* sumsq1 = S + 4096;
    float* scale1 = S + 8192;
    float* shift1 = S + 12288;
    float* sum3   = S + 16384;
    float* sumsq3 = S + 20480;
    float* scale3 = S + 24576;
    float* shift3 = S + 28672;

    hipMemsetAsync(d_ws, 0, 8 * 4096 * sizeof(float), stream);

    k_gemm1<<<P_ * STRIPS, 256, 0, stream>>>(x, W1, bias1, yb, sum1, sumsq1);
    k_finalize<<<F_ / 256, 256, 0, stream>>>(sum1, sumsq1, gamma1, beta1, scale1, shift1);
    k_gemm2<<<P_ * STRIPS, 256, 0, stream>>>(x, yb, W2, bias2, scale1, shift1, sum3, sumsq3);
    k_finalize<<<F_ / 256, 256, 0, stream>>>(sum3, sumsq3, gamma3, beta3, scale3, shift3);
    k_bn_tanh<<<2048, 256, 0, stream>>>(yb, scale3, shift3);
}